// Round 1
// baseline (3318.030 us; speedup 1.0000x reference)
//
#include <hip/hip_runtime.h>

#define H 51
#define G4 204  // 4*H

__device__ __forceinline__ float sigmoidf_(float x) {
    // 1/(1+e^-x); e^-x -> inf for very negative x gives 0 (correct limit)
    return 1.0f / (1.0f + __expf(-x));
}
__device__ __forceinline__ float tanhf_(float x) {
    // tanh(x) = 1 - 2/(e^{2x}+1); overflow of e^{2x} -> inf -> 1 (correct limit)
    return 1.0f - 2.0f / (1.0f + __expf(2.0f * x));
}

__global__ __launch_bounds__(256, 1)
void lstm_seq_kernel(const float* __restrict__ x,
                     const float* __restrict__ Wih1, const float* __restrict__ Whh1,
                     const float* __restrict__ bih1, const float* __restrict__ bhh1,
                     const float* __restrict__ Wih2, const float* __restrict__ Whh2,
                     const float* __restrict__ bih2, const float* __restrict__ bhh2,
                     const float* __restrict__ fcw, const float* __restrict__ fcb,
                     float* __restrict__ out, int T, int future)
{
    const int b   = blockIdx.x;
    const int tid = threadIdx.x;

    extern __shared__ float xld[];            // T floats: this batch row of x
    __shared__ __align__(16) float h1s[56];   // h1 broadcast (51 + pad, [51..55]=0)
    __shared__ __align__(16) float h2s[56];   // h2 broadcast
    __shared__ float gpre[G4];                // gate preactivations
    __shared__ float xnext[1];                // feedback input for future phase

    // ---- one-time staging ----
    for (int i = tid; i < T; i += 256) xld[i] = x[(size_t)b * T + i];
    if (tid < 56) { h1s[tid] = 0.f; h2s[tid] = 0.f; }

    // weights into registers: thread g owns gate-row g of each matrix
    float w1[52], w2i[52], w2h[52];
    float wx1 = 0.f, bias1 = 0.f, bias2 = 0.f;
    const int g = tid;
    if (g < G4) {
        wx1   = Wih1[g];
        bias1 = bih1[g] + bhh1[g];
        bias2 = bih2[g] + bhh2[g];
        #pragma unroll
        for (int k = 0; k < H; ++k) {
            w1[k]  = Whh1[g * H + k];
            w2i[k] = Wih2[g * H + k];
            w2h[k] = Whh2[g * H + k];
        }
    } else {
        #pragma unroll
        for (int k = 0; k < H; ++k) { w1[k] = 0.f; w2i[k] = 0.f; w2h[k] = 0.f; }
    }
    w1[51] = 0.f; w2i[51] = 0.f; w2h[51] = 0.f;   // pad lane (h*s[51]==0 anyway)

    const float fcw_l = (tid < H) ? fcw[tid] : 0.f;
    const float fcb_l = fcb[0];

    float c1 = 0.f, c2 = 0.f;   // cell state owned by threads 0..50

    __syncthreads();

    const int TT = T + future;
    for (int t = 0; t < TT; ++t) {
        const float xt = (t < T) ? xld[t] : xnext[0];

        // ---- layer 1 matvec: pre1 = b1 + wx1*xt + W_hh1[g,:] . h1 ----
        float a0 = 0.f, a1 = 0.f, a2 = 0.f, a3 = 0.f;
        const float4* h1v = (const float4*)h1s;
        #pragma unroll
        for (int k4 = 0; k4 < 13; ++k4) {
            const float4 hv = h1v[k4];
            a0 += w1[k4 * 4 + 0] * hv.x;
            a1 += w1[k4 * 4 + 1] * hv.y;
            a2 += w1[k4 * 4 + 2] * hv.z;
            a3 += w1[k4 * 4 + 3] * hv.w;
        }
        const float pre1 = bias1 + wx1 * xt + ((a0 + a1) + (a2 + a3));
        if (g < G4) gpre[g] = pre1;
        __syncthreads();

        // ---- layer 1 activation (threads 0..50) ----
        if (tid < H) {
            const float ig = sigmoidf_(gpre[tid]);
            const float fg = sigmoidf_(gpre[H + tid]);
            const float gg = tanhf_(gpre[2 * H + tid]);
            const float og = sigmoidf_(gpre[3 * H + tid]);
            c1 = fg * c1 + ig * gg;
            h1s[tid] = og * tanhf_(c1);
        }
        __syncthreads();

        // ---- layer 2 matvec: pre2 = b2 + W_ih2[g,:].h1 + W_hh2[g,:].h2 ----
        float b0 = 0.f, b1r = 0.f, b2r = 0.f, b3r = 0.f;
        const float4* h2v = (const float4*)h2s;
        #pragma unroll
        for (int k4 = 0; k4 < 13; ++k4) {
            const float4 h1x = h1v[k4];
            const float4 h2x = h2v[k4];
            b0  += w2i[k4 * 4 + 0] * h1x.x;
            b1r += w2i[k4 * 4 + 1] * h1x.y;
            b2r += w2i[k4 * 4 + 2] * h1x.z;
            b3r += w2i[k4 * 4 + 3] * h1x.w;
            b0  += w2h[k4 * 4 + 0] * h2x.x;
            b1r += w2h[k4 * 4 + 1] * h2x.y;
            b2r += w2h[k4 * 4 + 2] * h2x.z;
            b3r += w2h[k4 * 4 + 3] * h2x.w;
        }
        const float pre2 = bias2 + ((b0 + b1r) + (b2r + b3r));
        if (g < G4) gpre[g] = pre2;
        __syncthreads();

        // ---- layer 2 activation + fc output ----
        float h2new = 0.f;
        if (tid < H) {
            const float ig = sigmoidf_(gpre[tid]);
            const float fg = sigmoidf_(gpre[H + tid]);
            const float gg = tanhf_(gpre[2 * H + tid]);
            const float og = sigmoidf_(gpre[3 * H + tid]);
            c2 = fg * c2 + ig * gg;
            h2new = og * tanhf_(c2);
            h2s[tid] = h2new;
        }
        // fc reduce in wave 0 (h2new lives in wave-0 registers; lanes 51..63 = 0)
        if (tid < 64) {
            float v = h2new * fcw_l;
            #pragma unroll
            for (int off = 32; off > 0; off >>= 1) v += __shfl_xor(v, off, 64);
            if (tid == 0) {
                const float o = v + fcb_l;
                out[(size_t)b * TT + t] = o;
                xnext[0] = o;
            }
        }
        __syncthreads();
    }
}

extern "C" void kernel_launch(void* const* d_in, const int* in_sizes, int n_in,
                              void* d_out, int out_size, void* d_ws, size_t ws_size,
                              hipStream_t stream) {
    const float* x    = (const float*)d_in[0];
    const float* Wih1 = (const float*)d_in[1];
    const float* Whh1 = (const float*)d_in[2];
    const float* bih1 = (const float*)d_in[3];
    const float* bhh1 = (const float*)d_in[4];
    const float* Wih2 = (const float*)d_in[5];
    const float* Whh2 = (const float*)d_in[6];
    const float* bih2 = (const float*)d_in[7];
    const float* bhh2 = (const float*)d_in[8];
    const float* fcw  = (const float*)d_in[9];
    const float* fcb  = (const float*)d_in[10];
    float* out = (float*)d_out;

    const int B  = 256;                 // fixed by setup (H=51 likewise hardcoded)
    const int T  = in_sizes[0] / B;     // 2048
    const int TT = out_size / B;        // T + future
    const int future = TT - T;

    const size_t shmem = (size_t)T * sizeof(float);
    hipLaunchKernelGGL(lstm_seq_kernel, dim3(B), dim3(256), shmem, stream,
                       x, Wih1, Whh1, bih1, bhh1, Wih2, Whh2, bih2, bhh2,
                       fcw, fcb, out, T, future);
}

// Round 2
// 2741.062 us; speedup vs baseline: 1.2105x; 1.2105x over previous
//
#include <hip/hip_runtime.h>

#define H 51
#define G4 204

#define FOR13(M) M(0) M(1) M(2) M(3) M(4) M(5) M(6) M(7) M(8) M(9) M(10) M(11) M(12)

__global__ __launch_bounds__(256, 1)
void lstm_seq_kernel(const float* __restrict__ x,
                     const float* __restrict__ Wih1, const float* __restrict__ Whh1,
                     const float* __restrict__ bih1, const float* __restrict__ bhh1,
                     const float* __restrict__ Wih2, const float* __restrict__ Whh2,
                     const float* __restrict__ bih2, const float* __restrict__ bhh2,
                     const float* __restrict__ fcw, const float* __restrict__ fcb,
                     float* __restrict__ out, int T, int future)
{
    const int b   = blockIdx.x;
    const int tid = threadIdx.x;

    extern __shared__ float xld[];                 // [T] this batch row of x
    __shared__ __align__(16) float h1s[2][56];     // double-buffered h1 (pad->0)
    __shared__ __align__(16) float h2s[2][56];     // double-buffered h2
    __shared__ __align__(16) float fcs[56];        // fc weights
    __shared__ float xnext[1];                     // feedback input (future phase)

    for (int i = tid; i < T; i += 256) xld[i] = x[(size_t)b * T + i];
    if (tid < 56) {
        h1s[0][tid] = 0.f; h1s[1][tid] = 0.f;
        h2s[0][tid] = 0.f; h2s[1][tid] = 0.f;
        fcs[tid] = (tid < H) ? fcw[tid] : 0.f;
    }

    // lane mapping: tid = 4*u + g  (u = unit 0..50, g = gate 0:i 1:f 2:g 3:o)
    const int g = tid & 3;
    const int u = tid >> 2;
    const bool gate = (tid < G4);
    const bool isfc = (tid == G4);                 // solo fc thread (wave3 lane 12)
    const int row  = gate ? (g * H + u) : 0;       // row in 204-row weight mats

    // uniform activation: act = A / (1 + exp(m*x)) + B
    //   sigmoid: m=-1, A=1,  B=0   tanh: m=2, A=-2, B=1   inactive: A=B=0 -> 0
    const float mC = (gate && g == 2) ?  2.f : -1.f;
    const float Ac = gate ? ((g == 2) ? -2.f : 1.f) : 0.f;
    const float Bc = (gate && g == 2) ?  1.f : 0.f;

    const float wx1   = gate ? Wih1[row] : 0.f;
    const float bias1 = gate ? (bih1[row] + bhh1[row]) : 0.f;
    const float bias2 = gate ? (bih2[row] + bhh2[row]) : 0.f;
    const float fcb_l = fcb[0];

    // ---- weight rows in NAMED float4 registers (cannot be demoted) ----
    #define WDECL(P) float4 P##_0,P##_1,P##_2,P##_3,P##_4,P##_5,P##_6,P##_7,P##_8,P##_9,P##_10,P##_11,P##_12;
    WDECL(w1) WDECL(w2i) WDECL(w2h)
    {
        const float* p1 = Whh1 + (size_t)row * H;
        const float* p2 = Wih2 + (size_t)row * H;
        const float* p3 = Whh2 + (size_t)row * H;
        #define WL(P, S, i) P##_##i = make_float4(S[4*i], S[4*i+1], S[4*i+2], S[4*i+3]);
        #define WLOAD(P, S) WL(P,S,0) WL(P,S,1) WL(P,S,2) WL(P,S,3) WL(P,S,4) WL(P,S,5) \
                            WL(P,S,6) WL(P,S,7) WL(P,S,8) WL(P,S,9) WL(P,S,10) WL(P,S,11) \
                            P##_12 = make_float4(S[48], S[49], S[50], 0.f);
        WLOAD(w1,  p1)
        WLOAD(w2i, p2)
        WLOAD(w2h, p3)
    }

    const int gb = (tid & 63) & ~3;                // shfl group base within wave

    float c1 = 0.f, c2 = 0.f;                      // cell state, replicated per 4-lane group
    __syncthreads();

    const int TT = T + future;
    for (int t = 0; t < TT; ++t) {
        const int p = t & 1, q = p ^ 1;

        // ---- fc thread: out(t-1) = fcw . h2(t-1) + fcb (off critical path for t<T)
        if (isfc && t > 0) {
            const float4* hv = (const float4*)h2s[q];
            const float4* fv = (const float4*)fcs;
            float4 s = make_float4(0.f, 0.f, 0.f, 0.f);
            #define FCD(i) { const float4 h_ = hv[i], f_ = fv[i]; \
                s.x += h_.x*f_.x; s.y += h_.y*f_.y; s.z += h_.z*f_.z; s.w += h_.w*f_.w; }
            FOR13(FCD)
            const float o = (s.x + s.y) + (s.z + s.w) + fcb_l;
            out[(size_t)b * TT + (t - 1)] = o;
            xnext[0] = o;
        }
        if (t >= T) __syncthreads();               // future phase: out feeds back
        const float xt = (t < T) ? xld[t] : xnext[0];

        // ---- phase B: pre1 = b1 + wx1*xt + Whh1.h1(t-1) ; hh2 = Whh2.h2(t-1) ----
        float4 a = make_float4(0.f,0.f,0.f,0.f), d = make_float4(0.f,0.f,0.f,0.f);
        {
            const float4* h1v = (const float4*)h1s[q];
            const float4* h2v = (const float4*)h2s[q];
            #define MB(i) { const float4 h_ = h1v[i], y_ = h2v[i]; \
                a.x += w1_##i.x*h_.x;  a.y += w1_##i.y*h_.y;  a.z += w1_##i.z*h_.z;  a.w += w1_##i.w*h_.w; \
                d.x += w2h_##i.x*y_.x; d.y += w2h_##i.y*y_.y; d.z += w2h_##i.z*y_.z; d.w += w2h_##i.w*y_.w; }
            FOR13(MB)
        }
        const float pre1 = bias1 + wx1 * xt + ((a.x + a.y) + (a.z + a.w));
        const float hh2  = (d.x + d.y) + (d.z + d.w);

        float act = Ac / (1.f + __expf(mC * pre1)) + Bc;
        float si = __shfl(act, gb + 0);
        float sf = __shfl(act, gb + 1);
        float tg = __shfl(act, gb + 2);
        float so = __shfl(act, gb + 3);
        c1 = sf * c1 + si * tg;
        const float h1n = so * (1.f - 2.f / (1.f + __expf(2.f * c1)));
        if (gate && g == 0) h1s[p][u] = h1n;
        __syncthreads();                           // barrier 1: h1(t) visible

        // ---- phase C: pre2 = b2 + hh2 + Wih2.h1(t) ----
        float4 e = make_float4(0.f,0.f,0.f,0.f);
        {
            const float4* h1v = (const float4*)h1s[p];
            #define MC(i) { const float4 h_ = h1v[i]; \
                e.x += w2i_##i.x*h_.x; e.y += w2i_##i.y*h_.y; e.z += w2i_##i.z*h_.z; e.w += w2i_##i.w*h_.w; }
            FOR13(MC)
        }
        const float pre2 = bias2 + hh2 + ((e.x + e.y) + (e.z + e.w));
        act = Ac / (1.f + __expf(mC * pre2)) + Bc;
        si = __shfl(act, gb + 0);
        sf = __shfl(act, gb + 1);
        tg = __shfl(act, gb + 2);
        so = __shfl(act, gb + 3);
        c2 = sf * c2 + si * tg;
        const float h2n = so * (1.f - 2.f / (1.f + __expf(2.f * c2)));
        if (gate && g == 0) h2s[p][u] = h2n;
        __syncthreads();                           // barrier 2: h2(t) visible
    }

    // final output: out(TT-1) = fcw . h2(TT-1) + fcb
    if (isfc) {
        const float4* hv = (const float4*)h2s[(TT - 1) & 1];
        const float4* fv = (const float4*)fcs;
        float4 s = make_float4(0.f, 0.f, 0.f, 0.f);
        FOR13(FCD)
        out[(size_t)b * TT + (TT - 1)] = (s.x + s.y) + (s.z + s.w) + fcb_l;
    }
}

extern "C" void kernel_launch(void* const* d_in, const int* in_sizes, int n_in,
                              void* d_out, int out_size, void* d_ws, size_t ws_size,
                              hipStream_t stream) {
    const float* x    = (const float*)d_in[0];
    const float* Wih1 = (const float*)d_in[1];
    const float* Whh1 = (const float*)d_in[2];
    const float* bih1 = (const float*)d_in[3];
    const float* bhh1 = (const float*)d_in[4];
    const float* Wih2 = (const float*)d_in[5];
    const float* Whh2 = (const float*)d_in[6];
    const float* bih2 = (const float*)d_in[7];
    const float* bhh2 = (const float*)d_in[8];
    const float* fcw  = (const float*)d_in[9];
    const float* fcb  = (const float*)d_in[10];
    float* out = (float*)d_out;

    const int B  = 256;                 // fixed by setup (H=51 hardcoded)
    const int T  = in_sizes[0] / B;     // 2048
    const int TT = out_size / B;        // T + future
    const int future = TT - T;

    const size_t shmem = (size_t)T * sizeof(float);
    hipLaunchKernelGGL(lstm_seq_kernel, dim3(B), dim3(256), shmem, stream,
                       x, Wih1, Whh1, bih1, bhh1, Wih2, Whh2, bih2, bhh2,
                       fcw, fcb, out, T, future);
}

// Round 3
// 2641.976 us; speedup vs baseline: 1.2559x; 1.0375x over previous
//
#include <hip/hip_runtime.h>

#define H 51

__device__ __forceinline__ float rl_(float v, int lane) {
    return __builtin_bit_cast(float, __builtin_amdgcn_readlane(__builtin_bit_cast(int, v), lane));
}
template<int CTRL>
__device__ __forceinline__ float qb_(float v) {   // quad_perm broadcast (DPP, VALU pipe)
    return __builtin_bit_cast(float, __builtin_amdgcn_update_dpp(
        0, __builtin_bit_cast(int, v), CTRL, 0xf, 0xf, true));
}

// act = A * rcp(1 + exp2(m2*x)) + B   (sigmoid: m2=-log2e,A=1,B=0 ; tanh: m2=2log2e,A=-2,B=1)
__device__ __forceinline__ float act_(float x, float m2, float A, float B) {
    const float e = __builtin_amdgcn_exp2f(m2 * x);
    const float r = __builtin_amdgcn_rcpf(1.f + e);
    return fmaf(A, r, B);
}
__device__ __forceinline__ float tanh_(float c) {
    const float e = __builtin_amdgcn_exp2f(2.885390082f * c);
    const float r = __builtin_amdgcn_rcpf(1.f + e);
    return fmaf(-2.f, r, 1.f);
}

__global__ __launch_bounds__(256, 1)
void lstm_seq_kernel(const float* __restrict__ x,
                     const float* __restrict__ Wih1, const float* __restrict__ Whh1,
                     const float* __restrict__ bih1, const float* __restrict__ bhh1,
                     const float* __restrict__ Wih2, const float* __restrict__ Whh2,
                     const float* __restrict__ bih2, const float* __restrict__ bhh2,
                     const float* __restrict__ fcw, const float* __restrict__ fcb,
                     float* __restrict__ out, int T, int future)
{
    const int b   = blockIdx.x;
    const int tid = threadIdx.x;
    const int l   = tid & 63;          // lane
    const int w   = tid >> 6;          // wave 0..3
    const int uq  = l >> 2;            // unit-within-wave 0..15 (13 valid)
    const int g   = l & 3;             // gate 0:i 1:f 2:g 3:o
    const int u   = 13 * w + uq;       // unit 0..50
    const bool act_lane = (uq < 13) && (u < H);
    const bool g0lane   = act_lane && (g == 0);

    extern __shared__ float xld[];              // [T] this batch row of x
    __shared__ float h1s[2][64];                // double-buffered h1 (pad zeros)
    __shared__ float h2s[2][64];
    __shared__ __align__(16) float fcp[4];      // per-wave fc partial sums

    for (int i = tid; i < T; i += 256) xld[i] = x[(size_t)b * T + i];
    if (tid < 64) { h1s[0][tid] = 0.f; h1s[1][tid] = 0.f;
                    h2s[0][tid] = 0.f; h2s[1][tid] = 0.f; }
    if (tid < 4) fcp[tid] = 0.f;

    const int row = g * H + u;                  // only dereferenced when act_lane
    const float wx1   = act_lane ? Wih1[row] : 0.f;
    const float bias1 = act_lane ? (bih1[row] + bhh1[row]) : 0.f;
    const float bias2 = act_lane ? (bih2[row] + bhh2[row]) : 0.f;
    const float fcu   = g0lane ? fcw[u] : 0.f;
    const float fcb_l = fcb[0];

    // activation constants per gate lane
    const float m2A = (g == 2) ? 2.885390082f : -1.442695041f;
    const float Aa  = act_lane ? ((g == 2) ? -2.f : 1.f) : 0.f;
    const float Ba  = (act_lane && g == 2) ? 1.f : 0.f;

    // ---- weights: one row of each matrix per lane, pinned into VGPRs ----
    float w1[H], w2i[H], w2h[H];
    #pragma unroll
    for (int k = 0; k < H; ++k) {
        w1[k]  = act_lane ? Whh1[(size_t)row * H + k] : 0.f;
        w2i[k] = act_lane ? Wih2[(size_t)row * H + k] : 0.f;
        w2h[k] = act_lane ? Whh2[(size_t)row * H + k] : 0.f;
    }
    #pragma unroll
    for (int k = 0; k < H; ++k)
        asm volatile("" : "+v"(w1[k]), "+v"(w2i[k]), "+v"(w2h[k]));   // opaque: no reload, no spill-to-global

    float c1 = 0.f, c2 = 0.f;                   // cell state (replicated per quad)
    __syncthreads();

    const int TT = T + future;
    for (int t = 0; t < TT; ++t) {
        const int p = t & 1, q = p ^ 1;

        // ---- out(t-1) from fc partials; feedback input in future phase ----
        float xt;
        {
            float o = 0.f;
            if (t > 0) {
                const float4 f = *(const float4*)fcp;
                o = (f.x + f.y) + (f.z + f.w) + fcb_l;
                if (tid == 0) out[(size_t)b * TT + (t - 1)] = o;
            }
            xt = (t < T) ? xld[t] : o;
        }

        // ---- distribute h(t-1): one stride-1 b32 read per vector ----
        const float h1v = h1s[q][l];
        const float h2v = h2s[q][l];

        // ---- phase B: pre1 = b1 + wx1*xt + Whh1.h1 ; hh2 = Whh2.h2 ----
        float a0 = 0.f, a1 = 0.f, a2 = 0.f, a3 = 0.f;
        float d0 = 0.f, d1 = 0.f, d2 = 0.f, d3 = 0.f;
        #pragma unroll
        for (int k = 0; k < 48; k += 4) {
            a0 = fmaf(rl_(h1v, k + 0), w1[k + 0], a0);
            a1 = fmaf(rl_(h1v, k + 1), w1[k + 1], a1);
            a2 = fmaf(rl_(h1v, k + 2), w1[k + 2], a2);
            a3 = fmaf(rl_(h1v, k + 3), w1[k + 3], a3);
            d0 = fmaf(rl_(h2v, k + 0), w2h[k + 0], d0);
            d1 = fmaf(rl_(h2v, k + 1), w2h[k + 1], d1);
            d2 = fmaf(rl_(h2v, k + 2), w2h[k + 2], d2);
            d3 = fmaf(rl_(h2v, k + 3), w2h[k + 3], d3);
        }
        a0 = fmaf(rl_(h1v, 48), w1[48], a0);
        a1 = fmaf(rl_(h1v, 49), w1[49], a1);
        a2 = fmaf(rl_(h1v, 50), w1[50], a2);
        d0 = fmaf(rl_(h2v, 48), w2h[48], d0);
        d1 = fmaf(rl_(h2v, 49), w2h[49], d1);
        d2 = fmaf(rl_(h2v, 50), w2h[50], d2);

        const float pre1 = bias1 + fmaf(wx1, xt, (a0 + a1) + (a2 + a3));
        const float hh2  = (d0 + d1) + (d2 + d3);

        float act = act_(pre1, m2A, Aa, Ba);
        {
            const float si = qb_<0x00>(act);
            const float sf = qb_<0x55>(act);
            const float tg = qb_<0xAA>(act);
            const float so = qb_<0xFF>(act);
            c1 = fmaf(sf, c1, si * tg);
            const float h1n = so * tanh_(c1);
            if (g0lane) h1s[p][u] = h1n;
        }
        __syncthreads();                        // barrier 1: h1(t) visible

        // ---- phase C: pre2 = b2 + hh2 + Wih2.h1(t) ----
        const float h1vp = h1s[p][l];
        float e0 = 0.f, e1 = 0.f, e2 = 0.f, e3 = 0.f;
        #pragma unroll
        for (int k = 0; k < 48; k += 4) {
            e0 = fmaf(rl_(h1vp, k + 0), w2i[k + 0], e0);
            e1 = fmaf(rl_(h1vp, k + 1), w2i[k + 1], e1);
            e2 = fmaf(rl_(h1vp, k + 2), w2i[k + 2], e2);
            e3 = fmaf(rl_(h1vp, k + 3), w2i[k + 3], e3);
        }
        e0 = fmaf(rl_(h1vp, 48), w2i[48], e0);
        e1 = fmaf(rl_(h1vp, 49), w2i[49], e1);
        e2 = fmaf(rl_(h1vp, 50), w2i[50], e2);

        const float pre2 = bias2 + hh2 + ((e0 + e1) + (e2 + e3));
        act = act_(pre2, m2A, Aa, Ba);
        {
            const float si = qb_<0x00>(act);
            const float sf = qb_<0x55>(act);
            const float tg = qb_<0xAA>(act);
            const float so = qb_<0xFF>(act);
            c2 = fmaf(sf, c2, si * tg);
            const float h2n = so * tanh_(c2);
            if (g0lane) h2s[p][u] = h2n;

            // fc partial: sum over units of fcw[u]*h2n(u)  (g==0 lanes carry it)
            float pv = g0lane ? h2n * fcu : 0.f;
            pv += __shfl_xor(pv, 4, 64);
            pv += __shfl_xor(pv, 8, 64);
            pv += __shfl_xor(pv, 16, 64);
            pv += __shfl_xor(pv, 32, 64);
            if (l == 0) fcp[w] = pv;
        }
        __syncthreads();                        // barrier 2: h2(t) + fcp visible
    }

    if (tid == 0) {
        const float4 f = *(const float4*)fcp;
        out[(size_t)b * TT + (TT - 1)] = (f.x + f.y) + (f.z + f.w) + fcb_l;
    }
}

extern "C" void kernel_launch(void* const* d_in, const int* in_sizes, int n_in,
                              void* d_out, int out_size, void* d_ws, size_t ws_size,
                              hipStream_t stream) {
    const float* x    = (const float*)d_in[0];
    const float* Wih1 = (const float*)d_in[1];
    const float* Whh1 = (const float*)d_in[2];
    const float* bih1 = (const float*)d_in[3];
    const float* bhh1 = (const float*)d_in[4];
    const float* Wih2 = (const float*)d_in[5];
    const float* Whh2 = (const float*)d_in[6];
    const float* bih2 = (const float*)d_in[7];
    const float* bhh2 = (const float*)d_in[8];
    const float* fcw  = (const float*)d_in[9];
    const float* fcb  = (const float*)d_in[10];
    float* out = (float*)d_out;

    const int B  = 256;                 // fixed by setup (H=51 hardcoded)
    const int T  = in_sizes[0] / B;     // 2048
    const int TT = out_size / B;        // T + future
    const int future = TT - T;

    const size_t shmem = (size_t)T * sizeof(float);
    hipLaunchKernelGGL(lstm_seq_kernel, dim3(B), dim3(256), shmem, stream,
                       x, Wih1, Whh1, bih1, bhh1, Wih2, Whh2, bih2, bhh2,
                       fcw, fcb, out, T, future);
}